// Round 1
// baseline (429.257 us; speedup 1.0000x reference)
//
#include <hip/hip_runtime.h>
#include <hip/hip_bf16.h>
#include <stdint.h>

// Problem constants: B=16, S=1024, D=768, H=12, HD=64
// log2(e)/sqrt(64) folded into stored q so softmax runs in exp2 domain.
#define QSCALE 0.1803368801111204f

typedef unsigned short u16;
typedef __attribute__((ext_vector_type(8))) short short8;   // 8 bf16 = 4 VGPR
typedef __attribute__((ext_vector_type(4))) float f32x4;    // MFMA 16x16 acc

__device__ __forceinline__ u16 f2bf(float f) {  // RNE f32->bf16
  uint32_t x = __builtin_bit_cast(uint32_t, f);
  x += 0x7fffu + ((x >> 16) & 1u);
  return (u16)(x >> 16);
}

__device__ __forceinline__ void async16(const void* g, void* l) {
  __builtin_amdgcn_global_load_lds(
      (const __attribute__((address_space(1))) uint32_t*)g,
      (__attribute__((address_space(3))) uint32_t*)l, 16, 0, 0);
}

// ---------------------------------------------------------------- converts
__global__ void __launch_bounds__(256) k_convert_x(const float* __restrict__ x,
                                                   u16* __restrict__ xb) {
  const int n4 = (16 * 1024 * 768) / 4;
  int i = blockIdx.x * 256 + threadIdx.x;
  const int stride = gridDim.x * 256;
  for (; i < n4; i += stride) {
    float4 v = ((const float4*)x)[i];
    ushort4 u;
    u.x = f2bf(v.x); u.y = f2bf(v.y); u.z = f2bf(v.z); u.w = f2bf(v.w);
    ((ushort4*)xb)[i] = u;
  }
}

// wqkvT[n][d] = W{q,k,v}[d][n%768]  (n = proj*768 + h*64 + e), bf16
// woT[e][hhd] = Wo[hhd][e], bf16
__global__ void __launch_bounds__(256) k_convert_w(
    const float* __restrict__ Wq, const float* __restrict__ Wk,
    const float* __restrict__ Wv, const float* __restrict__ Wo,
    u16* __restrict__ wqkvT, u16* __restrict__ woT) {
  int idx = blockIdx.x * 256 + threadIdx.x;  // 9216*256 == 2359296 exact
  if (idx < 2304 * 768) {
    int nrow = idx / 768;
    int d = idx - nrow * 768;
    int proj = nrow / 768;
    int rem = nrow - proj * 768;
    const float* W = (proj == 0) ? Wq : ((proj == 1) ? Wk : Wv);
    wqkvT[idx] = f2bf(W[d * 768 + rem]);
  } else {
    int j = idx - 2304 * 768;
    int e = j / 768;
    int hhd = j - e * 768;
    woT[j] = f2bf(Wo[hhd * 768 + e]);
  }
}

// ---------------------------------------------------------------- GEMM core
// m97 structure: 128x128 tile, BK=32, 256 thr (4 waves 2x2), global_load_lds
// width16, 2-barrier K-step, 16 MFMA/wave/K-step. K fixed = 768 (24 iters).
// A: [M][768] bf16 row-major; B: [N][768] bf16 row-major (i.e. B^T input).
__device__ __forceinline__ void gemm_tile_k768(const u16* __restrict__ Atile,
                                               const u16* __restrict__ Btile,
                                               u16* As, u16* Bs,
                                               f32x4 acc[4][4]) {
  const int tid = threadIdx.x;
  const int lane = tid & 63, w = tid >> 6;
  const int wr = w >> 1, wc = w & 1;
  const int g = lane >> 4, cr = lane & 15;
  const int q0 = tid, q1 = tid + 256;
  const size_t ga0 = (size_t)(q0 >> 2) * 1536 + (size_t)((q0 & 3) * 16);
  const size_t ga1 = (size_t)(q1 >> 2) * 1536 + (size_t)((q1 & 3) * 16);

  for (int kt = 0; kt < 24; ++kt) {
    const char* Ag = (const char*)Atile + kt * 64;
    const char* Bg = (const char*)Btile + kt * 64;
    async16(Ag + ga0, (char*)As + q0 * 16);
    async16(Ag + ga1, (char*)As + q1 * 16);
    async16(Bg + ga0, (char*)Bs + q0 * 16);
    async16(Bg + ga1, (char*)Bs + q1 * 16);
    __syncthreads();  // drains vmcnt for global_load_lds
    short8 a[4], b[4];
#pragma unroll
    for (int i = 0; i < 4; ++i)
      a[i] = *(const short8*)(As + (wr * 64 + i * 16 + cr) * 32 + g * 8);
#pragma unroll
    for (int i = 0; i < 4; ++i)
      b[i] = *(const short8*)(Bs + (wc * 64 + i * 16 + cr) * 32 + g * 8);
#pragma unroll
    for (int mi = 0; mi < 4; ++mi)
#pragma unroll
      for (int ni = 0; ni < 4; ++ni)
        acc[mi][ni] = __builtin_amdgcn_mfma_f32_16x16x32_bf16(
            a[mi], b[ni], acc[mi][ni], 0, 0, 0);
    __syncthreads();
  }
}

// ------------------------------------------------------------- GEMM1: QKV
// C[m][n], m = b*1024+s (16384), n = proj*768 + h*64 + e (2304).
// q -> [B,H,S,HD] (scaled), k -> [B,H,S,HD], v -> [B,H,HD,S] (transposed!)
__global__ void __launch_bounds__(256) k_gemm_qkv(
    const u16* __restrict__ xb, const u16* __restrict__ wT,
    const float* __restrict__ bq, const float* __restrict__ bk,
    const float* __restrict__ bv,
    u16* __restrict__ qbuf, u16* __restrict__ kbuf, u16* __restrict__ vbuf) {
  __shared__ __align__(16) u16 As[128 * 32];
  __shared__ __align__(16) u16 Bs[128 * 32];
  f32x4 acc[4][4];
#pragma unroll
  for (int i = 0; i < 4; ++i)
#pragma unroll
    for (int j = 0; j < 4; ++j) acc[i][j] = (f32x4){0.f, 0.f, 0.f, 0.f};

  gemm_tile_k768(xb + (size_t)blockIdx.x * 128 * 768,
                 wT + (size_t)blockIdx.y * 128 * 768, As, Bs, acc);

  const int lane = threadIdx.x & 63, w = threadIdx.x >> 6;
  const int wr = w >> 1, wc = w & 1, g = lane >> 4, cr = lane & 15;
  const int mbase = blockIdx.x * 128 + wr * 64;
  const int nbase = blockIdx.y * 128 + wc * 64;
#pragma unroll
  for (int ni = 0; ni < 4; ++ni) {
    const int n = nbase + ni * 16 + cr;
    const int proj = n / 768;           // fragment never straddles (768%16==0)
    const int rem = n - proj * 768;     // h*64+e
    const int h = rem >> 6, e = rem & 63;
    const float bias = ((proj == 0) ? bq : (proj == 1) ? bk : bv)[rem];
#pragma unroll
    for (int mi = 0; mi < 4; ++mi) {
      const int mrow = mbase + mi * 16 + g * 4;
      const int b = mrow >> 10, s0 = mrow & 1023;
#pragma unroll
      for (int r = 0; r < 4; ++r) {
        const float val = acc[mi][ni][r] + bias;
        const int s = s0 + r;
        if (proj == 0) {
          qbuf[((size_t)(b * 12 + h) * 1024 + s) * 64 + e] = f2bf(val * QSCALE);
        } else if (proj == 1) {
          kbuf[((size_t)(b * 12 + h) * 1024 + s) * 64 + e] = f2bf(val);
        } else {
          vbuf[((size_t)(b * 12 + h) * 64 + e) * 1024 + s] = f2bf(val);
        }
      }
    }
  }
}

// --------------------------------------------------------------- attention
// 1 block = (b,h, 128 q rows); 4 waves x 32 q-rows. KV tiles of 64.
// K tile LDS [64 kv][64 hd], V^T tile LDS [64 hd][64 kv], both XOR-swizzled
// (byte ^= (row&7)<<4) via pre-swizzled global source (rule #21).
__global__ void __launch_bounds__(256) attn(const u16* __restrict__ qb,
                                            const u16* __restrict__ kb,
                                            const u16* __restrict__ vb,
                                            u16* __restrict__ ob) {
  __shared__ __align__(16) u16 Ks[64 * 64];
  __shared__ __align__(16) u16 Vs[64 * 64];
  __shared__ __align__(16) u16 Ps[4][32 * 64];  // per-wave P scratch

  const int bid = blockIdx.x;
  const int bh = bid >> 3, qi = bid & 7;
  const int tid = threadIdx.x, lane = tid & 63, w = tid >> 6;
  const int g = lane >> 4, cr = lane & 15;

  const u16* qbase = qb + ((size_t)bh * 1024 + qi * 128 + w * 32) * 64;
  const char* kbase = (const char*)(kb + (size_t)bh * 1024 * 64);
  const char* vbase = (const char*)(vb + (size_t)bh * 1024 * 64);

  // Q fragments in registers (pre-scaled by log2e/8 at projection time)
  short8 qf[2][2];
#pragma unroll
  for (int m = 0; m < 2; ++m)
#pragma unroll
    for (int kk = 0; kk < 2; ++kk)
      qf[m][kk] = *(const short8*)(qbase + (m * 16 + cr) * 64 + kk * 32 + g * 8);

  f32x4 O[2][4];
  float mrun[2][4], lrun[2][4];
#pragma unroll
  for (int m = 0; m < 2; ++m)
#pragma unroll
    for (int i = 0; i < 4; ++i) {
      O[m][i] = (f32x4){0.f, 0.f, 0.f, 0.f};
      mrun[m][i] = -1e30f;
      lrun[m][i] = 0.f;
    }

  const int q0 = tid, q1 = tid + 256;
  const int r0 = q0 >> 3, c0 = (q0 & 7) * 16;
  const int r1 = q1 >> 3, c1 = (q1 & 7) * 16;
  char* Psw = (char*)&Ps[w][0];

  for (int t = 0; t < 16; ++t) {
    // stage K (rows = kv, 128B each) and V^T (rows = hd, stride S*2)
    async16(kbase + (size_t)(t * 64 + r0) * 128 + (c0 ^ ((r0 & 7) << 4)),
            (char*)Ks + q0 * 16);
    async16(kbase + (size_t)(t * 64 + r1) * 128 + (c1 ^ ((r1 & 7) << 4)),
            (char*)Ks + q1 * 16);
    async16(vbase + (size_t)r0 * 2048 + t * 128 + (c0 ^ ((r0 & 7) << 4)),
            (char*)Vs + q0 * 16);
    async16(vbase + (size_t)r1 * 2048 + t * 128 + (c1 ^ ((r1 & 7) << 4)),
            (char*)Vs + q1 * 16);
    __syncthreads();

    // S = Q*K^T   (C layout: col = kv = cr, row = q = g*4 + reg)
    f32x4 sf[2][4];
#pragma unroll
    for (int m = 0; m < 2; ++m)
#pragma unroll
      for (int n = 0; n < 4; ++n) sf[m][n] = (f32x4){0.f, 0.f, 0.f, 0.f};
#pragma unroll
    for (int n = 0; n < 4; ++n) {
#pragma unroll
      for (int kk = 0; kk < 2; ++kk) {
        const int row = n * 16 + cr;
        const int c = kk * 64 + g * 16;
        short8 bf = *(const short8*)((char*)Ks + row * 128 + (c ^ ((row & 7) << 4)));
        sf[0][n] = __builtin_amdgcn_mfma_f32_16x16x32_bf16(qf[0][kk], bf, sf[0][n], 0, 0, 0);
        sf[1][n] = __builtin_amdgcn_mfma_f32_16x16x32_bf16(qf[1][kk], bf, sf[1][n], 0, 0, 0);
      }
    }

    // wave-parallel online softmax (exp2 domain; rows live in 16-lane groups)
#pragma unroll
    for (int m = 0; m < 2; ++m) {
#pragma unroll
      for (int r = 0; r < 4; ++r) {
        float mx = fmaxf(fmaxf(sf[m][0][r], sf[m][1][r]),
                         fmaxf(sf[m][2][r], sf[m][3][r]));
        mx = fmaxf(mx, __shfl_xor(mx, 1));
        mx = fmaxf(mx, __shfl_xor(mx, 2));
        mx = fmaxf(mx, __shfl_xor(mx, 4));
        mx = fmaxf(mx, __shfl_xor(mx, 8));
        const float mold = mrun[m][r];
        const float mnew = fmaxf(mold, mx);
        const float alpha = __builtin_amdgcn_exp2f(mold - mnew);
        mrun[m][r] = mnew;
        float rs = 0.f;
#pragma unroll
        for (int n = 0; n < 4; ++n) {
          const float p = __builtin_amdgcn_exp2f(sf[m][n][r] - mnew);
          sf[m][n][r] = p;
          rs += p;
        }
        rs += __shfl_xor(rs, 1);
        rs += __shfl_xor(rs, 2);
        rs += __shfl_xor(rs, 4);
        rs += __shfl_xor(rs, 8);
        lrun[m][r] = lrun[m][r] * alpha + rs;
#pragma unroll
        for (int nn = 0; nn < 4; ++nn) O[m][nn][r] *= alpha;
        // P -> bf16 -> per-wave LDS (swizzled), row = q, col = kv
        const int row = m * 16 + g * 4 + r;
        const int swz = (row & 7) << 4;
#pragma unroll
        for (int n = 0; n < 4; ++n) {
          const int col = n * 16 + cr;
          *(u16*)(Psw + row * 128 + ((col * 2) ^ swz)) = f2bf(sf[m][n][r]);
        }
      }
    }

    // O += P * V  (A = P from LDS, B = V^T tile)
    short8 pa[2][2];
#pragma unroll
    for (int m = 0; m < 2; ++m)
#pragma unroll
      for (int kk = 0; kk < 2; ++kk) {
        const int row = m * 16 + cr;
        const int c = kk * 64 + g * 16;
        pa[m][kk] = *(const short8*)(Psw + row * 128 + (c ^ ((row & 7) << 4)));
      }
#pragma unroll
    for (int nn = 0; nn < 4; ++nn) {
#pragma unroll
      for (int kk = 0; kk < 2; ++kk) {
        const int row = nn * 16 + cr;
        const int c = kk * 64 + g * 16;
        short8 bf = *(const short8*)((char*)Vs + row * 128 + (c ^ ((row & 7) << 4)));
        O[0][nn] = __builtin_amdgcn_mfma_f32_16x16x32_bf16(pa[0][kk], bf, O[0][nn], 0, 0, 0);
        O[1][nn] = __builtin_amdgcn_mfma_f32_16x16x32_bf16(pa[1][kk], bf, O[1][nn], 0, 0, 0);
      }
    }
    __syncthreads();  // protect Ks/Vs before next stage
  }

  // epilogue: o[b][s][h*64+hd] bf16 (K-contiguous for output projection)
  const int b = bh / 12, h = bh - b * 12;
#pragma unroll
  for (int m = 0; m < 2; ++m)
#pragma unroll
    for (int r = 0; r < 4; ++r) {
      const float inv = 1.0f / lrun[m][r];
      const int s = qi * 128 + w * 32 + m * 16 + g * 4 + r;
      const size_t rowoff = (size_t)(b * 1024 + s) * 768 + h * 64;
#pragma unroll
      for (int nn = 0; nn < 4; ++nn)
        ob[rowoff + nn * 16 + cr] = f2bf(O[m][nn][r] * inv);
    }
}

// ------------------------------------------------------------ GEMM2: out
__global__ void __launch_bounds__(256) k_gemm_out(
    const u16* __restrict__ obuf, const u16* __restrict__ woT,
    const float* __restrict__ bo, float* __restrict__ out) {
  __shared__ __align__(16) u16 As[128 * 32];
  __shared__ __align__(16) u16 Bs[128 * 32];
  f32x4 acc[4][4];
#pragma unroll
  for (int i = 0; i < 4; ++i)
#pragma unroll
    for (int j = 0; j < 4; ++j) acc[i][j] = (f32x4){0.f, 0.f, 0.f, 0.f};

  gemm_tile_k768(obuf + (size_t)blockIdx.x * 128 * 768,
                 woT + (size_t)blockIdx.y * 128 * 768, As, Bs, acc);

  const int lane = threadIdx.x & 63, w = threadIdx.x >> 6;
  const int wr = w >> 1, wc = w & 1, g = lane >> 4, cr = lane & 15;
  const int mbase = blockIdx.x * 128 + wr * 64;
  const int nbase = blockIdx.y * 128 + wc * 64;
#pragma unroll
  for (int ni = 0; ni < 4; ++ni) {
    const int n = nbase + ni * 16 + cr;
    const float bias = bo[n];
#pragma unroll
    for (int mi = 0; mi < 4; ++mi) {
      const int mrow = mbase + mi * 16 + g * 4;
#pragma unroll
      for (int r = 0; r < 4; ++r)
        out[(size_t)(mrow + r) * 768 + n] = acc[mi][ni][r] + bias;
    }
  }
}

// ---------------------------------------------------------------- launch
extern "C" void kernel_launch(void* const* d_in, const int* in_sizes, int n_in,
                              void* d_out, int out_size, void* d_ws, size_t ws_size,
                              hipStream_t stream) {
  const float* x  = (const float*)d_in[0];
  const float* Wq = (const float*)d_in[1];
  const float* bq = (const float*)d_in[2];
  const float* Wk = (const float*)d_in[3];
  const float* bk = (const float*)d_in[4];
  const float* Wv = (const float*)d_in[5];
  const float* bv = (const float*)d_in[6];
  const float* Wo = (const float*)d_in[7];
  const float* bo = (const float*)d_in[8];
  float* out = (float*)d_out;

  char* ws = (char*)d_ws;
  u16* xb    = (u16*)(ws);                  // 16384x768 bf16      = 25165824 B
  u16* wqkvT = (u16*)(ws + 25165824);       // 2304x768            =  3538944 B
  u16* woT   = (u16*)(ws + 28704768);       // 768x768             =  1179648 B
  u16* qbuf  = (u16*)(ws + 29884416);       // [B,H,S,HD]          = 25165824 B
  u16* kbuf  = (u16*)(ws + 55050240);       // [B,H,S,HD]          = 25165824 B
  u16* vbuf  = (u16*)(ws + 80216064);       // [B,H,HD,S]          = 25165824 B
  u16* obuf  = (u16*)(ws + 105381888);      // [B,S,H*HD]          = 25165824 B
                                            // total 130547712 B

  k_convert_x<<<4096, 256, 0, stream>>>(x, xb);
  k_convert_w<<<9216, 256, 0, stream>>>(Wq, Wk, Wv, Wo, wqkvT, woT);
  k_gemm_qkv<<<dim3(128, 18), 256, 0, stream>>>(xb, wqkvT, bq, bk, bv,
                                                qbuf, kbuf, vbuf);
  attn<<<1536, 256, 0, stream>>>(qbuf, kbuf, vbuf, obuf);
  k_gemm_out<<<dim3(128, 6), 256, 0, stream>>>(obuf, woT, bo, out);
}

// Round 3
// 373.026 us; speedup vs baseline: 1.1507x; 1.1507x over previous
//
#include <hip/hip_runtime.h>
#include <hip/hip_bf16.h>
#include <stdint.h>

// Problem constants: B=16, S=1024, D=768, H=12, HD=64
// log2(e)/sqrt(64) folded into stored q so softmax runs in exp2 domain.
#define QSCALE 0.1803368801111204f

typedef unsigned short u16;
typedef __attribute__((ext_vector_type(8))) short short8;   // 8 bf16 = 4 VGPR
typedef __attribute__((ext_vector_type(4))) float f32x4;    // MFMA 16x16 acc

__device__ __forceinline__ u16 f2bf(float f) {  // RNE f32->bf16
  uint32_t x = __builtin_bit_cast(uint32_t, f);
  x += 0x7fffu + ((x >> 16) & 1u);
  return (u16)(x >> 16);
}

__device__ __forceinline__ uint32_t pack2bf(float lo, float hi) {
  return (uint32_t)f2bf(lo) | ((uint32_t)f2bf(hi) << 16);
}

__device__ __forceinline__ void async16(const void* g, void* l) {
  __builtin_amdgcn_global_load_lds(
      (const __attribute__((address_space(1))) uint32_t*)g,
      (__attribute__((address_space(3))) uint32_t*)l, 16, 0, 0);
}

// ---------------------------------------------------------------- converts
__global__ void __launch_bounds__(256) k_convert_x(const float* __restrict__ x,
                                                   u16* __restrict__ xb) {
  const int n4 = (16 * 1024 * 768) / 4;
  int i = blockIdx.x * 256 + threadIdx.x;
  const int stride = gridDim.x * 256;
  for (; i < n4; i += stride) {
    float4 v = ((const float4*)x)[i];
    ushort4 u;
    u.x = f2bf(v.x); u.y = f2bf(v.y); u.z = f2bf(v.z); u.w = f2bf(v.w);
    ((ushort4*)xb)[i] = u;
  }
}

// wqkvT[n][d] = W{q,k,v}[d][n%768]  (n = proj*768 + h*64 + e), bf16
// woT[e][hhd] = Wo[hhd][e], bf16
__global__ void __launch_bounds__(256) k_convert_w(
    const float* __restrict__ Wq, const float* __restrict__ Wk,
    const float* __restrict__ Wv, const float* __restrict__ Wo,
    u16* __restrict__ wqkvT, u16* __restrict__ woT) {
  int idx = blockIdx.x * 256 + threadIdx.x;  // 9216*256 == 2359296 exact
  if (idx < 2304 * 768) {
    int nrow = idx / 768;
    int d = idx - nrow * 768;
    int proj = nrow / 768;
    int rem = nrow - proj * 768;
    const float* W = (proj == 0) ? Wq : ((proj == 1) ? Wk : Wv);
    wqkvT[idx] = f2bf(W[d * 768 + rem]);
  } else {
    int j = idx - 2304 * 768;
    int e = j / 768;
    int hhd = j - e * 768;
    woT[j] = f2bf(Wo[hhd * 768 + e]);
  }
}

// ---------------------------------------------------------------- GEMM core
// m97 structure: 128x128 tile, BK=32, 256 thr (4 waves 2x2), global_load_lds
// width16, 2-barrier K-step, 16 MFMA/wave/K-step. K fixed = 768 (24 iters).
// A: [M][768] bf16 row-major; B: [N][768] bf16 row-major (i.e. B^T input).
__device__ __forceinline__ void gemm_tile_k768(const u16* __restrict__ Atile,
                                               const u16* __restrict__ Btile,
                                               u16* As, u16* Bs,
                                               f32x4 acc[4][4]) {
  const int tid = threadIdx.x;
  const int lane = tid & 63, w = tid >> 6;
  const int wr = w >> 1, wc = w & 1;
  const int g = lane >> 4, cr = lane & 15;
  const int q0 = tid, q1 = tid + 256;
  const size_t ga0 = (size_t)(q0 >> 2) * 1536 + (size_t)((q0 & 3) * 16);
  const size_t ga1 = (size_t)(q1 >> 2) * 1536 + (size_t)((q1 & 3) * 16);

  for (int kt = 0; kt < 24; ++kt) {
    const char* Ag = (const char*)Atile + kt * 64;
    const char* Bg = (const char*)Btile + kt * 64;
    async16(Ag + ga0, (char*)As + q0 * 16);
    async16(Ag + ga1, (char*)As + q1 * 16);
    async16(Bg + ga0, (char*)Bs + q0 * 16);
    async16(Bg + ga1, (char*)Bs + q1 * 16);
    __syncthreads();  // drains vmcnt for global_load_lds
    short8 a[4], b[4];
#pragma unroll
    for (int i = 0; i < 4; ++i)
      a[i] = *(const short8*)(As + (wr * 64 + i * 16 + cr) * 32 + g * 8);
#pragma unroll
    for (int i = 0; i < 4; ++i)
      b[i] = *(const short8*)(Bs + (wc * 64 + i * 16 + cr) * 32 + g * 8);
#pragma unroll
    for (int mi = 0; mi < 4; ++mi)
#pragma unroll
      for (int ni = 0; ni < 4; ++ni)
        acc[mi][ni] = __builtin_amdgcn_mfma_f32_16x16x32_bf16(
            a[mi], b[ni], acc[mi][ni], 0, 0, 0);
    __syncthreads();
  }
}

// ------------------------------------------------------------- GEMM1: QKV
__global__ void __launch_bounds__(256) k_gemm_qkv(
    const u16* __restrict__ xb, const u16* __restrict__ wT,
    const float* __restrict__ bq, const float* __restrict__ bk,
    const float* __restrict__ bv,
    u16* __restrict__ qbuf, u16* __restrict__ kbuf, u16* __restrict__ vbuf) {
  __shared__ __align__(16) u16 As[128 * 32];
  __shared__ __align__(16) u16 Bs[128 * 32];
  f32x4 acc[4][4];
#pragma unroll
  for (int i = 0; i < 4; ++i)
#pragma unroll
    for (int j = 0; j < 4; ++j) acc[i][j] = (f32x4){0.f, 0.f, 0.f, 0.f};

  gemm_tile_k768(xb + (size_t)blockIdx.x * 128 * 768,
                 wT + (size_t)blockIdx.y * 128 * 768, As, Bs, acc);

  const int lane = threadIdx.x & 63, w = threadIdx.x >> 6;
  const int wr = w >> 1, wc = w & 1, g = lane >> 4, cr = lane & 15;
  const int mbase = blockIdx.x * 128 + wr * 64;
  const int nbase = blockIdx.y * 128 + wc * 64;
#pragma unroll
  for (int ni = 0; ni < 4; ++ni) {
    const int n = nbase + ni * 16 + cr;
    const int proj = n / 768;           // fragment never straddles (768%16==0)
    const int rem = n - proj * 768;     // h*64+e
    const int h = rem >> 6, e = rem & 63;
    const float bias = ((proj == 0) ? bq : (proj == 1) ? bk : bv)[rem];
#pragma unroll
    for (int mi = 0; mi < 4; ++mi) {
      const int mrow = mbase + mi * 16 + g * 4;
      const int b = mrow >> 10, s0 = mrow & 1023;
#pragma unroll
      for (int r = 0; r < 4; ++r) {
        const float val = acc[mi][ni][r] + bias;
        const int s = s0 + r;
        if (proj == 0) {
          qbuf[((size_t)(b * 12 + h) * 1024 + s) * 64 + e] = f2bf(val * QSCALE);
        } else if (proj == 1) {
          kbuf[((size_t)(b * 12 + h) * 1024 + s) * 64 + e] = f2bf(val);
        } else {
          vbuf[((size_t)(b * 12 + h) * 64 + e) * 1024 + s] = f2bf(val);
        }
      }
    }
  }
}

// --------------------------------------------------------------- attention
// 1 block = (b,h, 128 q rows); 4 waves x 32 q-rows. KV tiles of 64.
// Swapped QK^T: S^T = mfma(K, Q) so each lane owns ONE q-column per half
// (softmax reduce = 15 in-lane ops + 2 shfl). Double-buffered K/V staging
// (issue next tile before compute; one __syncthreads per tile). T1 chunked
// XCD swizzle keeps all 8 q-tiles of a (b,h) on one XCD for K/V L2 reuse.
__global__ void __launch_bounds__(256) attn(const u16* __restrict__ qb,
                                            const u16* __restrict__ kb,
                                            const u16* __restrict__ vb,
                                            u16* __restrict__ ob) {
  __shared__ __align__(16) u16 Ks[2][64 * 64];
  __shared__ __align__(16) u16 Vs[2][64 * 64];
  __shared__ __align__(16) u16 Ps[4][32 * 64];  // per-wave P scratch

  // T1 chunked swizzle: launched i runs on XCD i%8; give each XCD 192
  // consecutive logical blocks = 24 complete (b,h) groups.
  const int lb = (blockIdx.x & 7) * 192 + (blockIdx.x >> 3);
  const int bh = lb >> 3, qi = lb & 7;
  const int tid = threadIdx.x, lane = tid & 63, w = tid >> 6;
  const int g = lane >> 4, cr = lane & 15;

  const u16* qbase = qb + ((size_t)bh * 1024 + qi * 128 + w * 32) * 64;
  const char* kbase = (const char*)(kb + (size_t)bh * 1024 * 64);
  const char* vbase = (const char*)(vb + (size_t)bh * 1024 * 64);

  // Q fragments in registers (pre-scaled by log2e/8 at projection time)
  short8 qf[2][2];
#pragma unroll
  for (int m = 0; m < 2; ++m)
#pragma unroll
    for (int kk = 0; kk < 2; ++kk)
      qf[m][kk] = *(const short8*)(qbase + (m * 16 + cr) * 64 + kk * 32 + g * 8);

  f32x4 O[2][4];
  float mrun[2], lrun[2];
#pragma unroll
  for (int m = 0; m < 2; ++m) {
#pragma unroll
    for (int i = 0; i < 4; ++i) O[m][i] = (f32x4){0.f, 0.f, 0.f, 0.f};
    mrun[m] = -1e30f;
    lrun[m] = 0.f;
  }

  const int q0 = tid, q1 = tid + 256;
  const int r0 = q0 >> 3, sc0 = ((q0 & 7) * 16) ^ ((r0 & 7) << 4);
  const int r1 = q1 >> 3, sc1 = ((q1 & 7) * 16) ^ ((r1 & 7) << 4);
  char* Psw = (char*)&Ps[w][0];

#define STAGE(buf, t)                                                        \
  do {                                                                       \
    async16(kbase + (size_t)((t)*64 + r0) * 128 + sc0, (char*)Ks[buf] + q0 * 16); \
    async16(kbase + (size_t)((t)*64 + r1) * 128 + sc1, (char*)Ks[buf] + q1 * 16); \
    async16(vbase + (size_t)r0 * 2048 + (t)*128 + sc0, (char*)Vs[buf] + q0 * 16); \
    async16(vbase + (size_t)r1 * 2048 + (t)*128 + sc1, (char*)Vs[buf] + q1 * 16); \
  } while (0)

  STAGE(0, 0);
  __syncthreads();  // drain prologue loads
  int cur = 0;

  for (int t = 0; t < 16; ++t) {
    if (t < 15) STAGE(cur ^ 1, t + 1);  // issue next tile early (hides HBM)

    // ---- S^T = K * Q^T : C[row=kv_local][col=q_local]
    short8 kf[4][2];
#pragma unroll
    for (int n = 0; n < 4; ++n)
#pragma unroll
      for (int kk = 0; kk < 2; ++kk) {
        const int row = n * 16 + cr;
        kf[n][kk] = *(const short8*)((char*)Ks[cur] + row * 128 +
                                     ((kk * 64 + g * 16) ^ ((row & 7) << 4)));
      }
    f32x4 sT[4][2];  // [kv-frag n][q-half m]
#pragma unroll
    for (int n = 0; n < 4; ++n)
#pragma unroll
      for (int m = 0; m < 2; ++m) sT[n][m] = (f32x4){0.f, 0.f, 0.f, 0.f};
    __builtin_amdgcn_s_setprio(1);
#pragma unroll
    for (int n = 0; n < 4; ++n)
#pragma unroll
      for (int kk = 0; kk < 2; ++kk) {
        sT[n][0] = __builtin_amdgcn_mfma_f32_16x16x32_bf16(kf[n][kk], qf[0][kk], sT[n][0], 0, 0, 0);
        sT[n][1] = __builtin_amdgcn_mfma_f32_16x16x32_bf16(kf[n][kk], qf[1][kk], sT[n][1], 0, 0, 0);
      }
    __builtin_amdgcn_s_setprio(0);

    // ---- online softmax: lane owns q = m*16+cr; kv in-lane {n*16+g*4+r}
    float alpha_m[2];
#pragma unroll
    for (int m = 0; m < 2; ++m) {
      float mx = sT[0][m][0];
#pragma unroll
      for (int n = 0; n < 4; ++n)
#pragma unroll
        for (int r = 0; r < 4; ++r) mx = fmaxf(mx, sT[n][m][r]);
      mx = fmaxf(mx, __shfl_xor(mx, 16));
      mx = fmaxf(mx, __shfl_xor(mx, 32));
      const float mold = mrun[m];
      const float mnew = fmaxf(mold, mx);
      const float al = __builtin_amdgcn_exp2f(mold - mnew);
      mrun[m] = mnew;
      alpha_m[m] = al;
      float rs = 0.f;
#pragma unroll
      for (int n = 0; n < 4; ++n)
#pragma unroll
        for (int r = 0; r < 4; ++r) {
          const float p = __builtin_amdgcn_exp2f(sT[n][m][r] - mnew);
          sT[n][m][r] = p;
          rs += p;
        }
      rs += __shfl_xor(rs, 16);
      rs += __shfl_xor(rs, 32);
      lrun[m] = lrun[m] * al + rs;
      // P -> bf16 pairs -> per-wave LDS (swizzled): row=q, col=kv
      const int q = m * 16 + cr;
      const int swz = (q & 7) << 4;
      char* prow = Psw + q * 128;
#pragma unroll
      for (int n = 0; n < 4; ++n)
#pragma unroll
        for (int pp = 0; pp < 2; ++pp) {
          const int kvb = (n * 16 + g * 4 + 2 * pp) * 2;
          *(uint32_t*)(prow + (kvb ^ swz)) =
              pack2bf(sT[n][m][2 * pp], sT[n][m][2 * pp + 1]);
        }
    }

    // ---- rescale O (alpha for q_local=g*4+r lives at lane with cr=g*4+r)
#pragma unroll
    for (int m = 0; m < 2; ++m)
#pragma unroll
      for (int r = 0; r < 4; ++r) {
        const float aO = __shfl(alpha_m[m], (g << 4) + g * 4 + r, 64);
#pragma unroll
        for (int nn = 0; nn < 4; ++nn) O[m][nn][r] *= aO;
      }

    // ---- O += P * V : A=P (rows=q), B=V (cols=hd) -> C[row=q][col=hd]
    short8 pf[2][2];
#pragma unroll
    for (int m = 0; m < 2; ++m)
#pragma unroll
      for (int kk = 0; kk < 2; ++kk) {
        const int q = m * 16 + cr;
        pf[m][kk] = *(const short8*)(Psw + q * 128 +
                                     ((kk * 64 + g * 16) ^ ((q & 7) << 4)));
      }
    short8 vf[4][2];
#pragma unroll
    for (int nn = 0; nn < 4; ++nn)
#pragma unroll
      for (int kk = 0; kk < 2; ++kk) {
        const int row = nn * 16 + cr;
        vf[nn][kk] = *(const short8*)((char*)Vs[cur] + row * 128 +
                                      ((kk * 64 + g * 16) ^ ((row & 7) << 4)));
      }
    __builtin_amdgcn_s_setprio(1);
#pragma unroll
    for (int nn = 0; nn < 4; ++nn)
#pragma unroll
      for (int kk = 0; kk < 2; ++kk) {
        O[0][nn] = __builtin_amdgcn_mfma_f32_16x16x32_bf16(pf[0][kk], vf[nn][kk], O[0][nn], 0, 0, 0);
        O[1][nn] = __builtin_amdgcn_mfma_f32_16x16x32_bf16(pf[1][kk], vf[nn][kk], O[1][nn], 0, 0, 0);
      }
    __builtin_amdgcn_s_setprio(0);

    __syncthreads();  // drain next-tile loads + protect Ks/Vs reuse
    cur ^= 1;
  }
#undef STAGE

  // epilogue: o[b][s][h*64+hd] bf16; row q = m*16+g*4+r, col hd = nn*16+cr
  const int b = bh / 12, h = bh - b * 12;
#pragma unroll
  for (int m = 0; m < 2; ++m)
#pragma unroll
    for (int r = 0; r < 4; ++r) {
      const float l = __shfl(lrun[m], (g << 4) + g * 4 + r, 64);
      const float inv = 1.0f / l;
      const int s = qi * 128 + w * 32 + m * 16 + g * 4 + r;
      const size_t rowoff = (size_t)(b * 1024 + s) * 768 + h * 64;
#pragma unroll
      for (int nn = 0; nn < 4; ++nn)
        ob[rowoff + nn * 16 + cr] = f2bf(O[m][nn][r] * inv);
    }
}

// ------------------------------------------------------------ GEMM2: out
__global__ void __launch_bounds__(256) k_gemm_out(
    const u16* __restrict__ obuf, const u16* __restrict__ woT,
    const float* __restrict__ bo, float* __restrict__ out) {
  __shared__ __align__(16) u16 As[128 * 32];
  __shared__ __align__(16) u16 Bs[128 * 32];
  f32x4 acc[4][4];
#pragma unroll
  for (int i = 0; i < 4; ++i)
#pragma unroll
    for (int j = 0; j < 4; ++j) acc[i][j] = (f32x4){0.f, 0.f, 0.f, 0.f};

  gemm_tile_k768(obuf + (size_t)blockIdx.x * 128 * 768,
                 woT + (size_t)blockIdx.y * 128 * 768, As, Bs, acc);

  const int lane = threadIdx.x & 63, w = threadIdx.x >> 6;
  const int wr = w >> 1, wc = w & 1, g = lane >> 4, cr = lane & 15;
  const int mbase = blockIdx.x * 128 + wr * 64;
  const int nbase = blockIdx.y * 128 + wc * 64;
#pragma unroll
  for (int ni = 0; ni < 4; ++ni) {
    const int n = nbase + ni * 16 + cr;
    const float bias = bo[n];
#pragma unroll
    for (int mi = 0; mi < 4; ++mi) {
      const int mrow = mbase + mi * 16 + g * 4;
#pragma unroll
      for (int r = 0; r < 4; ++r)
        out[(size_t)(mrow + r) * 768 + n] = acc[mi][ni][r] + bias;
    }
  }
}

// ---------------------------------------------------------------- launch
extern "C" void kernel_launch(void* const* d_in, const int* in_sizes, int n_in,
                              void* d_out, int out_size, void* d_ws, size_t ws_size,
                              hipStream_t stream) {
  const float* x  = (const float*)d_in[0];
  const float* Wq = (const float*)d_in[1];
  const float* bq = (const float*)d_in[2];
  const float* Wk = (const float*)d_in[3];
  const float* bk = (const float*)d_in[4];
  const float* Wv = (const float*)d_in[5];
  const float* bv = (const float*)d_in[6];
  const float* Wo = (const float*)d_in[7];
  const float* bo = (const float*)d_in[8];
  float* out = (float*)d_out;

  char* ws = (char*)d_ws;
  u16* xb    = (u16*)(ws);                  // 16384x768 bf16      = 25165824 B
  u16* wqkvT = (u16*)(ws + 25165824);       // 2304x768            =  3538944 B
  u16* woT   = (u16*)(ws + 28704768);       // 768x768             =  1179648 B
  u16* qbuf  = (u16*)(ws + 29884416);       // [B,H,S,HD]          = 25165824 B
  u16* kbuf  = (u16*)(ws + 55050240);       // [B,H,S,HD]          = 25165824 B
  u16* vbuf  = (u16*)(ws + 80216064);       // [B,H,HD,S]          = 25165824 B
  u16* obuf  = (u16*)(ws + 105381888);      // [B,S,H*HD]          = 25165824 B
                                            // total 130547712 B

  k_convert_x<<<4096, 256, 0, stream>>>(x, xb);
  k_convert_w<<<9216, 256, 0, stream>>>(Wq, Wk, Wv, Wo, wqkvT, woT);
  k_gemm_qkv<<<dim3(128, 18), 256, 0, stream>>>(xb, wqkvT, bq, bk, bv,
                                                qbuf, kbuf, vbuf);
  attn<<<1536, 256, 0, stream>>>(qbuf, kbuf, vbuf, obuf);
  k_gemm_out<<<dim3(128, 6), 256, 0, stream>>>(obuf, woT, bo, out);
}

// Round 7
// 368.200 us; speedup vs baseline: 1.1658x; 1.0131x over previous
//
#include <hip/hip_runtime.h>
#include <hip/hip_bf16.h>
#include <stdint.h>

// Problem constants: B=16, S=1024, D=768, H=12, HD=64
// log2(e)/sqrt(64) folded into stored q so softmax runs in exp2 domain.
#define QSCALE 0.1803368801111204f

typedef unsigned short u16;
typedef __attribute__((ext_vector_type(8))) short short8;   // 8 bf16 = 4 VGPR
typedef __attribute__((ext_vector_type(4))) float f32x4;    // MFMA 16x16 acc

__device__ __forceinline__ u16 f2bf(float f) {  // RNE f32->bf16
  uint32_t x = __builtin_bit_cast(uint32_t, f);
  x += 0x7fffu + ((x >> 16) & 1u);
  return (u16)(x >> 16);
}

__device__ __forceinline__ uint32_t cvtpk(float lo, float hi) {
  uint32_t r;
  asm("v_cvt_pk_bf16_f32 %0, %1, %2" : "=v"(r) : "v"(lo), "v"(hi));
  return r;
}

__device__ __forceinline__ void async16(const void* g, void* l) {
  __builtin_amdgcn_global_load_lds(
      (const __attribute__((address_space(1))) uint32_t*)g,
      (__attribute__((address_space(3))) uint32_t*)l, 16, 0, 0);
}

// ---------------------------------------------------------------- converts
__global__ void __launch_bounds__(256) k_convert_x(const float* __restrict__ x,
                                                   u16* __restrict__ xb) {
  const int n4 = (16 * 1024 * 768) / 4;
  int i = blockIdx.x * 256 + threadIdx.x;
  const int stride = gridDim.x * 256;
  for (; i < n4; i += stride) {
    float4 v = ((const float4*)x)[i];
    uint2 u;
    u.x = cvtpk(v.x, v.y);
    u.y = cvtpk(v.z, v.w);
    ((uint2*)xb)[i] = u;
  }
}

// wqkvT[n][d] = W{q,k,v}[d][n%768]  (n = proj*768 + h*64 + e), bf16
// woT[e][hhd] = Wo[hhd][e], bf16
__global__ void __launch_bounds__(256) k_convert_w(
    const float* __restrict__ Wq, const float* __restrict__ Wk,
    const float* __restrict__ Wv, const float* __restrict__ Wo,
    u16* __restrict__ wqkvT, u16* __restrict__ woT) {
  int idx = blockIdx.x * 256 + threadIdx.x;  // 9216*256 == 2359296 exact
  if (idx < 2304 * 768) {
    int nrow = idx / 768;
    int d = idx - nrow * 768;
    int proj = nrow / 768;
    int rem = nrow - proj * 768;
    const float* W = (proj == 0) ? Wq : ((proj == 1) ? Wk : Wv);
    wqkvT[idx] = f2bf(W[d * 768 + rem]);
  } else {
    int j = idx - 2304 * 768;
    int e = j / 768;
    int hhd = j - e * 768;
    woT[j] = f2bf(Wo[hhd * 768 + e]);
  }
}

// ---------------------------------------------------------------- GEMM core
// m97 structure: 128x128 tile, BK=32, 256 thr (4 waves 2x2), global_load_lds
// width16, 2-barrier K-step, 16 MFMA/wave/K-step. K fixed = 768 (24 iters).
// A: [M][768] bf16 row-major; B: [N][768] bf16 row-major (i.e. B^T input).
__device__ __forceinline__ void gemm_tile_k768(const u16* __restrict__ Atile,
                                               const u16* __restrict__ Btile,
                                               u16* As, u16* Bs,
                                               f32x4 acc[4][4]) {
  const int tid = threadIdx.x;
  const int lane = tid & 63, w = tid >> 6;
  const int wr = w >> 1, wc = w & 1;
  const int g = lane >> 4, cr = lane & 15;
  const int q0 = tid, q1 = tid + 256;
  const size_t ga0 = (size_t)(q0 >> 2) * 1536 + (size_t)((q0 & 3) * 16);
  const size_t ga1 = (size_t)(q1 >> 2) * 1536 + (size_t)((q1 & 3) * 16);

  for (int kt = 0; kt < 24; ++kt) {
    const char* Ag = (const char*)Atile + kt * 64;
    const char* Bg = (const char*)Btile + kt * 64;
    async16(Ag + ga0, (char*)As + q0 * 16);
    async16(Ag + ga1, (char*)As + q1 * 16);
    async16(Bg + ga0, (char*)Bs + q0 * 16);
    async16(Bg + ga1, (char*)Bs + q1 * 16);
    __syncthreads();  // drains vmcnt for global_load_lds
    short8 a[4], b[4];
#pragma unroll
    for (int i = 0; i < 4; ++i)
      a[i] = *(const short8*)(As + (wr * 64 + i * 16 + cr) * 32 + g * 8);
#pragma unroll
    for (int i = 0; i < 4; ++i)
      b[i] = *(const short8*)(Bs + (wc * 64 + i * 16 + cr) * 32 + g * 8);
#pragma unroll
    for (int mi = 0; mi < 4; ++mi)
#pragma unroll
      for (int ni = 0; ni < 4; ++ni)
        acc[mi][ni] = __builtin_amdgcn_mfma_f32_16x16x32_bf16(
            a[mi], b[ni], acc[mi][ni], 0, 0, 0);
    __syncthreads();
  }
}

// ------------------------------------------------------------- GEMM1: QKV
// 1-D grid 2304 = 8 XCD chunks x 288; within chunk y-minor (by = lb%18) so
// the 3.5MB weight set stays L2-resident and each A-panel is reused 18x.
__global__ void __launch_bounds__(256) k_gemm_qkv(
    const u16* __restrict__ xb, const u16* __restrict__ wT,
    const float* __restrict__ bq, const float* __restrict__ bk,
    const float* __restrict__ bv,
    u16* __restrict__ qbuf, u16* __restrict__ kbuf, u16* __restrict__ vbuf) {
  __shared__ __align__(16) u16 As[128 * 32];
  __shared__ __align__(16) u16 Bs[128 * 32];
  const int lb = (blockIdx.x & 7) * 288 + (blockIdx.x >> 3);
  const int bx = lb / 18, by = lb - bx * 18;

  f32x4 acc[4][4];
#pragma unroll
  for (int i = 0; i < 4; ++i)
#pragma unroll
    for (int j = 0; j < 4; ++j) acc[i][j] = (f32x4){0.f, 0.f, 0.f, 0.f};

  gemm_tile_k768(xb + (size_t)bx * 128 * 768,
                 wT + (size_t)by * 128 * 768, As, Bs, acc);

  const int lane = threadIdx.x & 63, w = threadIdx.x >> 6;
  const int wr = w >> 1, wc = w & 1, g = lane >> 4, cr = lane & 15;
  const int mbase = bx * 128 + wr * 64;
  const int nbase = by * 128 + wc * 64;
#pragma unroll
  for (int ni = 0; ni < 4; ++ni) {
    const int n = nbase + ni * 16 + cr;
    const int proj = n / 768;           // fragment never straddles (768%16==0)
    const int rem = n - proj * 768;     // h*64+e
    const int h = rem >> 6, e = rem & 63;
    const float bias = ((proj == 0) ? bq : (proj == 1) ? bk : bv)[rem];
#pragma unroll
    for (int mi = 0; mi < 4; ++mi) {
      const int mrow = mbase + mi * 16 + g * 4;
      const int b = mrow >> 10, s0 = mrow & 1023;
#pragma unroll
      for (int r = 0; r < 4; ++r) {
        const float val = acc[mi][ni][r] + bias;
        const int s = s0 + r;
        if (proj == 0) {
          qbuf[((size_t)(b * 12 + h) * 1024 + s) * 64 + e] = f2bf(val * QSCALE);
        } else if (proj == 1) {
          kbuf[((size_t)(b * 12 + h) * 1024 + s) * 64 + e] = f2bf(val);
        } else {
          vbuf[((size_t)(b * 12 + h) * 64 + e) * 1024 + s] = f2bf(val);
        }
      }
    }
  }
}

// --------------------------------------------------------------- attention
// 1 block = (b,h, 128 q rows); 4 waves x 32 q-rows. KV tiles of 64.
// Swapped QK^T (S^T = mfma(K,Q)): lane owns one q-column per half.
// T13 defer-max (THR=8, exp2 domain): skip O-rescale + alpha broadcasts
// unless the tile max exceeds running max by >8. P->bf16 via v_cvt_pk,
// written as ds_write_b64 pairs.
__global__ void __launch_bounds__(256) attn(const u16* __restrict__ qb,
                                            const u16* __restrict__ kb,
                                            const u16* __restrict__ vb,
                                            u16* __restrict__ ob) {
  __shared__ __align__(16) u16 Ks[2][64 * 64];
  __shared__ __align__(16) u16 Vs[2][64 * 64];
  __shared__ __align__(16) u16 Ps[4][32 * 64];  // per-wave P scratch

  // T1 chunked swizzle: launched i runs on XCD i%8; give each XCD 192
  // consecutive logical blocks = 24 complete (b,h) groups.
  const int lb = (blockIdx.x & 7) * 192 + (blockIdx.x >> 3);
  const int bh = lb >> 3, qi = lb & 7;
  const int tid = threadIdx.x, lane = tid & 63, w = tid >> 6;
  const int g = lane >> 4, cr = lane & 15;

  const u16* qbase = qb + ((size_t)bh * 1024 + qi * 128 + w * 32) * 64;
  const char* kbase = (const char*)(kb + (size_t)bh * 1024 * 64);
  const char* vbase = (const char*)(vb + (size_t)bh * 1024 * 64);

  // Q fragments in registers (pre-scaled by log2e/8 at projection time)
  short8 qf[2][2];
#pragma unroll
  for (int m = 0; m < 2; ++m)
#pragma unroll
    for (int kk = 0; kk < 2; ++kk)
      qf[m][kk] = *(const short8*)(qbase + (m * 16 + cr) * 64 + kk * 32 + g * 8);

  f32x4 O[2][4];
  float mrun[2], lrun[2];
#pragma unroll
  for (int m = 0; m < 2; ++m) {
#pragma unroll
    for (int i = 0; i < 4; ++i) O[m][i] = (f32x4){0.f, 0.f, 0.f, 0.f};
    mrun[m] = -1e30f;
    lrun[m] = 0.f;
  }

  const int q0 = tid, q1 = tid + 256;
  const int r0 = q0 >> 3, sc0 = ((q0 & 7) * 16) ^ ((r0 & 7) << 4);
  const int r1 = q1 >> 3, sc1 = ((q1 & 7) * 16) ^ ((r1 & 7) << 4);
  char* Psw = (char*)&Ps[w][0];

#define STAGE(buf, t)                                                        \
  do {                                                                       \
    async16(kbase + (size_t)((t)*64 + r0) * 128 + sc0, (char*)Ks[buf] + q0 * 16); \
    async16(kbase + (size_t)((t)*64 + r1) * 128 + sc1, (char*)Ks[buf] + q1 * 16); \
    async16(vbase + (size_t)r0 * 2048 + (t)*128 + sc0, (char*)Vs[buf] + q0 * 16); \
    async16(vbase + (size_t)r1 * 2048 + (t)*128 + sc1, (char*)Vs[buf] + q1 * 16); \
  } while (0)

  STAGE(0, 0);
  __syncthreads();  // drain prologue loads
  int cur = 0;

  for (int t = 0; t < 16; ++t) {
    if (t < 15) STAGE(cur ^ 1, t + 1);  // issue next tile early (hides HBM)

    // ---- S^T = K * Q^T : C[row=kv_local][col=q_local]
    short8 kf[4][2];
#pragma unroll
    for (int n = 0; n < 4; ++n)
#pragma unroll
      for (int kk = 0; kk < 2; ++kk) {
        const int row = n * 16 + cr;
        kf[n][kk] = *(const short8*)((char*)Ks[cur] + row * 128 +
                                     ((kk * 64 + g * 16) ^ ((row & 7) << 4)));
      }
    f32x4 sT[4][2];  // [kv-frag n][q-half m]
#pragma unroll
    for (int n = 0; n < 4; ++n)
#pragma unroll
      for (int m = 0; m < 2; ++m) sT[n][m] = (f32x4){0.f, 0.f, 0.f, 0.f};
    __builtin_amdgcn_s_setprio(1);
#pragma unroll
    for (int n = 0; n < 4; ++n)
#pragma unroll
      for (int kk = 0; kk < 2; ++kk) {
        sT[n][0] = __builtin_amdgcn_mfma_f32_16x16x32_bf16(kf[n][kk], qf[0][kk], sT[n][0], 0, 0, 0);
        sT[n][1] = __builtin_amdgcn_mfma_f32_16x16x32_bf16(kf[n][kk], qf[1][kk], sT[n][1], 0, 0, 0);
      }
    __builtin_amdgcn_s_setprio(0);

    // ---- tile max per q-column (tree shape -> v_max3 fusable)
    float mx[2];
#pragma unroll
    for (int m = 0; m < 2; ++m) {
      float t0 = fmaxf(fmaxf(sT[0][m][0], sT[0][m][1]), fmaxf(sT[0][m][2], sT[0][m][3]));
      float t1 = fmaxf(fmaxf(sT[1][m][0], sT[1][m][1]), fmaxf(sT[1][m][2], sT[1][m][3]));
      float t2 = fmaxf(fmaxf(sT[2][m][0], sT[2][m][1]), fmaxf(sT[2][m][2], sT[2][m][3]));
      float t3 = fmaxf(fmaxf(sT[3][m][0], sT[3][m][1]), fmaxf(sT[3][m][2], sT[3][m][3]));
      float v = fmaxf(fmaxf(t0, t1), fmaxf(t2, t3));
      v = fmaxf(v, __shfl_xor(v, 16));
      v = fmaxf(v, __shfl_xor(v, 32));
      mx[m] = v;
    }

    // ---- T13 defer-max: rescale only when some column grew by > 8
    if (!__all(mx[0] <= mrun[0] + 8.f && mx[1] <= mrun[1] + 8.f)) {
      float al[2];
#pragma unroll
      for (int m = 0; m < 2; ++m) {
        const float mnew = fmaxf(mrun[m], mx[m]);
        al[m] = __builtin_amdgcn_exp2f(mrun[m] - mnew);
        mrun[m] = mnew;
        lrun[m] *= al[m];
      }
#pragma unroll
      for (int m = 0; m < 2; ++m)
#pragma unroll
        for (int r = 0; r < 4; ++r) {
          const float aO = __shfl(al[m], (g << 4) + g * 4 + r, 64);
#pragma unroll
          for (int nn = 0; nn < 4; ++nn) O[m][nn][r] *= aO;
        }
    }

    // ---- P = exp2(S - m), row-sum, pack to bf16, write b64 to Ps
#pragma unroll
    for (int m = 0; m < 2; ++m) {
      const float mm = mrun[m];
      float rs = 0.f;
      const int q = m * 16 + cr;
      const int swz = (q & 7) << 4;
      char* prow = Psw + q * 128;
#pragma unroll
      for (int n = 0; n < 4; ++n) {
        float p0 = __builtin_amdgcn_exp2f(sT[n][m][0] - mm);
        float p1 = __builtin_amdgcn_exp2f(sT[n][m][1] - mm);
        float p2 = __builtin_amdgcn_exp2f(sT[n][m][2] - mm);
        float p3 = __builtin_amdgcn_exp2f(sT[n][m][3] - mm);
        rs += (p0 + p1) + (p2 + p3);
        uint2 pw;
        pw.x = cvtpk(p0, p1);
        pw.y = cvtpk(p2, p3);
        *(uint2*)(prow + ((n * 32 + g * 8) ^ swz)) = pw;
      }
      rs += __shfl_xor(rs, 16);
      rs += __shfl_xor(rs, 32);
      lrun[m] += rs;
    }

    // ---- O += P * V : A=P (rows=q), B=V (cols=hd) -> C[row=q][col=hd]
    short8 pf[2][2];
#pragma unroll
    for (int m = 0; m < 2; ++m)
#pragma unroll
      for (int kk = 0; kk < 2; ++kk) {
        const int q = m * 16 + cr;
        pf[m][kk] = *(const short8*)(Psw + q * 128 +
                                     ((kk * 64 + g * 16) ^ ((q & 7) << 4)));
      }
    short8 vf[4][2];
#pragma unroll
    for (int nn = 0; nn < 4; ++nn)
#pragma unroll
      for (int kk = 0; kk < 2; ++kk) {
        const int row = nn * 16 + cr;
        vf[nn][kk] = *(const short8*)((char*)Vs[cur] + row * 128 +
                                      ((kk * 64 + g * 16) ^ ((row & 7) << 4)));
      }
    __builtin_amdgcn_s_setprio(1);
#pragma unroll
    for (int nn = 0; nn < 4; ++nn)
#pragma unroll
      for (int kk = 0; kk < 2; ++kk) {
        O[0][nn] = __builtin_amdgcn_mfma_f32_16x16x32_bf16(pf[0][kk], vf[nn][kk], O[0][nn], 0, 0, 0);
        O[1][nn] = __builtin_amdgcn_mfma_f32_16x16x32_bf16(pf[1][kk], vf[nn][kk], O[1][nn], 0, 0, 0);
      }
    __builtin_amdgcn_s_setprio(0);

    __syncthreads();  // drain next-tile loads + protect Ks/Vs reuse
    cur ^= 1;
  }
#undef STAGE

  // epilogue: o[b][s][h*64+hd] bf16; row q = m*16+g*4+r, col hd = nn*16+cr
  const int b = bh / 12, h = bh - b * 12;
#pragma unroll
  for (int m = 0; m < 2; ++m)
#pragma unroll
    for (int r = 0; r < 4; ++r) {
      const float l = __shfl(lrun[m], (g << 4) + g * 4 + r, 64);
      const float inv = 1.0f / l;
      const int s = qi * 128 + w * 32 + m * 16 + g * 4 + r;
      const size_t rowoff = (size_t)(b * 1024 + s) * 768 + h * 64;
#pragma unroll
      for (int nn = 0; nn < 4; ++nn)
        ob[rowoff + nn * 16 + cr] = f2bf(O[m][nn][r] * inv);
    }
}

// ------------------------------------------------------------ GEMM2: out
// 1-D grid 768 = 8 XCD chunks x 96; y-minor (by = lb%6).
__global__ void __launch_bounds__(256) k_gemm_out(
    const u16* __restrict__ obuf, const u16* __restrict__ woT,
    const float* __restrict__ bo, float* __restrict__ out) {
  __shared__ __align__(16) u16 As[128 * 32];
  __shared__ __align__(16) u16 Bs[128 * 32];
  const int lb = (blockIdx.x & 7) * 96 + (blockIdx.x >> 3);
  const int bx = lb / 6, by = lb - bx * 6;

  f32x4 acc[4][4];
#pragma unroll
  for (int i = 0; i < 4; ++i)
#pragma unroll
    for (int j = 0; j < 4; ++j) acc[i][j] = (f32x4){0.f, 0.f, 0.f, 0.f};

  gemm_tile_k768(obuf + (size_t)bx * 128 * 768,
                 woT + (size_t)by * 128 * 768, As, Bs, acc);

  const int lane = threadIdx.x & 63, w = threadIdx.x >> 6;
  const int wr = w >> 1, wc = w & 1, g = lane >> 4, cr = lane & 15;
  const int mbase = bx * 128 + wr * 64;
  const int nbase = by * 128 + wc * 64;
#pragma unroll
  for (int ni = 0; ni < 4; ++ni) {
    const int n = nbase + ni * 16 + cr;
    const float bias = bo[n];
#pragma unroll
    for (int mi = 0; mi < 4; ++mi) {
      const int mrow = mbase + mi * 16 + g * 4;
#pragma unroll
      for (int r = 0; r < 4; ++r)
        out[(size_t)(mrow + r) * 768 + n] = acc[mi][ni][r] + bias;
    }
  }
}

// ---------------------------------------------------------------- launch
extern "C" void kernel_launch(void* const* d_in, const int* in_sizes, int n_in,
                              void* d_out, int out_size, void* d_ws, size_t ws_size,
                              hipStream_t stream) {
  const float* x  = (const float*)d_in[0];
  const float* Wq = (const float*)d_in[1];
  const float* bq = (const float*)d_in[2];
  const float* Wk = (const float*)d_in[3];
  const float* bk = (const float*)d_in[4];
  const float* Wv = (const float*)d_in[5];
  const float* bv = (const float*)d_in[6];
  const float* Wo = (const float*)d_in[7];
  const float* bo = (const float*)d_in[8];
  float* out = (float*)d_out;

  char* ws = (char*)d_ws;
  u16* xb    = (u16*)(ws);                  // 16384x768 bf16      = 25165824 B
  u16* wqkvT = (u16*)(ws + 25165824);       // 2304x768            =  3538944 B
  u16* woT   = (u16*)(ws + 28704768);       // 768x768             =  1179648 B
  u16* qbuf  = (u16*)(ws + 29884416);       // [B,H,S,HD]          = 25165824 B
  u16* kbuf  = (u16*)(ws + 55050240);       // [B,H,S,HD]          = 25165824 B
  u16* vbuf  = (u16*)(ws + 80216064);       // [B,H,HD,S]          = 25165824 B
  u16* obuf  = (u16*)(ws + 105381888);      // [B,S,H*HD]          = 25165824 B
                                            // total 130547712 B

  k_convert_x<<<4096, 256, 0, stream>>>(x, xb);
  k_convert_w<<<9216, 256, 0, stream>>>(Wq, Wk, Wv, Wo, wqkvT, woT);
  k_gemm_qkv<<<2304, 256, 0, stream>>>(xb, wqkvT, bq, bk, bv,
                                       qbuf, kbuf, vbuf);
  attn<<<1536, 256, 0, stream>>>(qbuf, kbuf, vbuf, obuf);
  k_gemm_out<<<768, 256, 0, stream>>>(obuf, woT, bo, out);
}